// Round 10
// baseline (65.428 us; speedup 1.0000x reference)
//
#include <hip/hip_runtime.h>
#include <math.h>

#define I_DIM 1024
#define S_DIM 512
#define O_DIM 1024
#define T_DIM 2048
#define B_SZ 4
#define M_ROWS (B_SZ * T_DIM)   // 8192
#define EPSF 1e-6f

// scan chunking: chunk length == GEMM BM (64)
#define CL 64
#define NCH 32   // NCH*CL == T_DIM

typedef _Float16 f16;
typedef __attribute__((ext_vector_type(8))) _Float16 f16x8;
typedef __attribute__((ext_vector_type(2))) _Float16 f16x2;
typedef __attribute__((ext_vector_type(4))) float f32x4;

__device__ __forceinline__ unsigned short f2h_bits(float f) {
    _Float16 h = (_Float16)f;
    return __builtin_bit_cast(unsigned short, h);
}

// async 16B global -> LDS (wave-uniform LDS base + lane*16; per-thread dest
// = base + tid*16 matches HW layout exactly -> LINEAR dest only)
__device__ __forceinline__ void load16_lds(const void* g, void* l) {
    __builtin_amdgcn_global_load_lds((const __attribute__((address_space(1))) void*)g,
                                     (__attribute__((address_space(3))) void*)l,
                                     16, 0, 0);
}

// ---------------------------------------------------------------------------
// prep: weight transposes only.
//   blocks [0,512)    : Bt16[s,i] = f16( B[i,s] * sigmoid(dt[s]) * nw[i] )
//   blocks [512,1024) : Ct16[o,s] = f16( C[s,o] )
// ---------------------------------------------------------------------------
__global__ __launch_bounds__(256)
void prep_w(const float* __restrict__ Bmat, const float* __restrict__ dt,
            const float* __restrict__ nw, unsigned short* __restrict__ Bt16,
            const float* __restrict__ Cmat, unsigned short* __restrict__ Ct16) {
    __shared__ float tile[32][33];
    const int t = threadIdx.x;
    const int tx = t & 31, ty = t >> 5;
    const int bx = blockIdx.x;
    if (bx < 512) {
        const int bs = (bx & 15) * 32;   // s block
        const int bi = (bx >> 4) * 32;   // i block
        #pragma unroll
        for (int i = ty; i < 32; i += 8)
            tile[i][tx] = Bmat[(size_t)(bi + i) * S_DIM + bs + tx];
        __syncthreads();
        const float w = nw[bi + tx];
        #pragma unroll
        for (int i = ty; i < 32; i += 8) {
            const int s = bs + i;
            const float dts = 1.0f / (1.0f + expf(-dt[s]));
            Bt16[(size_t)s * I_DIM + bi + tx] = f2h_bits(tile[tx][i] * dts * w);
        }
    } else {
        const int tb = bx - 512;
        const int bo = (tb & 31) * 32;   // o block
        const int bs = (tb >> 5) * 32;   // s block
        #pragma unroll
        for (int i = ty; i < 32; i += 8)
            tile[i][tx] = Cmat[(size_t)(bs + i) * O_DIM + bo + tx];
        __syncthreads();
        #pragma unroll
        for (int i = ty; i < 32; i += 8)
            Ct16[(size_t)(bo + i) * S_DIM + bs + tx] = f2h_bits(tile[tx][i]);
    }
}

// ---------------------------------------------------------------------------
// GEMM1 fused with RMSNorm + scan pass-1.  Reads fp32 u DIRECTLY.
// up[m,s] = rs[m] * sum_i f16(u[m,i]) * Bt[s,i],  rs from in-loop sumsq.
// Pipeline: 3 LDS slots, 3 A-reg sets, 1 barrier/iter.
//   iter kt: lgkm0 -> vmcnt(4) [retires B(kt), A-regs(kt+1); B(kt+1),
//   A(kt+2), B(kt+2) stay in flight] -> barrier -> writeA(kt+1) ->
//   loadA(kt+3) -> stageB(kt+2) -> ds_read kt -> 8 MFMA.
// A-regs get 2 full k-steps of slack (covers ~900cy cold-HBM u latency).
// Both-sides XOR chunk swizzle on As/Bs (rule 21). Full unroll: static
// slot/set indices + vmcnt immediates.
// ---------------------------------------------------------------------------
__global__ __launch_bounds__(256)
void gemm1_rms_chfin(const float* __restrict__ U, const f16* __restrict__ Bt,
                     f16* __restrict__ up, float* __restrict__ chlast,
                     const float* __restrict__ dt, const float* __restrict__ Avec) {
    constexpr int K = I_DIM, N = S_DIM, NK = K / 32;   // 32 k-steps
    __shared__ f16 As[3][64 * 32];    // 12 KB
    __shared__ f16 Bs[3][128 * 32];   // 24 KB
    __shared__ float rsbuf[64];
    const int t = threadIdx.x;

    // XCD swizzle (512 = 8*64): 4 consecutive logical bids share an A panel
    int bid = blockIdx.x;
    bid = (bid & 7) * 64 + (bid >> 3);
    const int n0 = (bid & 3) * 128;       // 4 n-blocks
    const int m0 = (bid >> 2) * 64;       // 128 m-blocks
    const int wid = t >> 6, lane = t & 63;
    const int wn = wid * 32, lr = lane & 15, kg = lane >> 4;

    // source-side chunk swizzle (matches read side)
    const int swch = (t & 3) ^ ((t >> 3) & 3);
    const float* aptr = U + (size_t)(m0 + (t >> 2)) * K + swch * 8;   // fp32 rows
    const f16*  bptr = Bt + (size_t)(n0 + (t >> 2)) * K + swch * 8;   // f16 rows
    const int rchunk = (kg ^ ((lr >> 1) & 3)) * 8;
    f16* adst = (f16*)&As[0][0] + t * 8;                 // + slot*2048

    float ss = 0.f;
    f32x4 acc[4][2];
    #pragma unroll
    for (int i = 0; i < 4; ++i)
        #pragma unroll
        for (int j = 0; j < 2; ++j) acc[i][j] = (f32x4){0.f, 0.f, 0.f, 0.f};

    float4 Ar0[2], Ar1[2], Ar2[2];       // three A reg sets (8 fp32 each)
    auto aset = [&](int i) -> float4* { return i == 0 ? Ar0 : (i == 1 ? Ar1 : Ar2); };

    auto loadA = [&](int kt, float4* r) {
        r[0] = *(const float4*)(aptr + kt * 32);
        r[1] = *(const float4*)(aptr + kt * 32 + 4);
    };
    auto stageB = [&](int kt, int slot) {
        load16_lds(bptr + kt * 32, &Bs[slot][t * 8]);
        load16_lds(bptr + (size_t)64 * K + kt * 32, &Bs[slot][2048 + t * 8]);
    };
    auto writeA = [&](const float4* r, int slot) {
        ss += r[0].x * r[0].x + r[0].y * r[0].y + r[0].z * r[0].z + r[0].w * r[0].w
            + r[1].x * r[1].x + r[1].y * r[1].y + r[1].z * r[1].z + r[1].w * r[1].w;
        f16x8 h = { (_Float16)r[0].x, (_Float16)r[0].y, (_Float16)r[0].z, (_Float16)r[0].w,
                    (_Float16)r[1].x, (_Float16)r[1].y, (_Float16)r[1].z, (_Float16)r[1].w };
        *(f16x8*)(adst + slot * 2048) = h;
    };

    // prologue: A(0),B(0),A(1),B(1),A(2) in flight; write A(0)
    loadA(0, Ar0); stageB(0, 0);
    loadA(1, Ar1); stageB(1, 1);
    loadA(2, Ar2);
    asm volatile("s_waitcnt vmcnt(8)");    // A(0) regs landed
    writeA(Ar0, 0);

    #pragma unroll
    for (int kt = 0; kt < NK; ++kt) {
        asm volatile("s_waitcnt lgkmcnt(0)");          // my ds_write visible
        if (kt <= NK - 3)      asm volatile("s_waitcnt vmcnt(4)");
        else if (kt == NK - 2) asm volatile("s_waitcnt vmcnt(2)");
        else                   asm volatile("s_waitcnt vmcnt(0)");
        __builtin_amdgcn_s_barrier();                  // tile kt fully in LDS
        __builtin_amdgcn_sched_barrier(0);

        if (kt + 1 < NK) writeA(aset((kt + 1) % 3), (kt + 1) % 3);
        if (kt + 3 < NK) loadA(kt + 3, aset((kt + 3) % 3));   // 2-step slack
        if (kt + 2 < NK) stageB(kt + 2, (kt + 2) % 3);

        const int slot = kt % 3;
        f16x8 af[4], bf[2];
        #pragma unroll
        for (int m = 0; m < 4; ++m)
            af[m] = *(const f16x8*)&As[slot][(m * 16 + lr) * 32 + rchunk];
        #pragma unroll
        for (int n = 0; n < 2; ++n)
            bf[n] = *(const f16x8*)&Bs[slot][(wn + n * 16 + lr) * 32 + rchunk];
        __builtin_amdgcn_s_setprio(1);
        #pragma unroll
        for (int m = 0; m < 4; ++m)
            #pragma unroll
            for (int n = 0; n < 2; ++n)
                acc[m][n] = __builtin_amdgcn_mfma_f32_16x16x32_f16(af[m], bf[n], acc[m][n], 0, 0, 0);
        __builtin_amdgcn_s_setprio(0);
    }

    // rs per row: 4 threads share a row -> xor-reduce sumsq
    ss += __shfl_xor(ss, 1, 64);
    ss += __shfl_xor(ss, 2, 64);
    if ((t & 3) == 0) rsbuf[t >> 2] = rsqrtf(ss * (1.0f / K) + EPSF);
    __syncthreads();

    // epilogue: up = rs*acc (f16) + fused chunk-final (fp32)
    // C/D layout: col = lane&15, row = (lane>>4)*4 + reg
    const int cb = m0 >> 11;               // batch
    const int cc = (m0 >> 6) & (NCH - 1);  // chunk
    #pragma unroll
    for (int n = 0; n < 2; ++n) {
        const int col = n0 + wn + n * 16 + lr;
        const float dts = 1.0f / (1.0f + expf(-dt[col]));
        const float e = dts * fabsf(Avec[col]);
        const float ainv = expf(e);        // a^-1
        float partial = 0.f;
        #pragma unroll
        for (int m = 0; m < 4; ++m) {
            const int row = m * 16 + kg * 4;
            f32x4 rs4 = *(const f32x4*)&rsbuf[row];
            float wgt = expf(-e * (float)(63 - row));   // a^(63-row)
            #pragma unroll
            for (int j = 0; j < 4; ++j) {
                const float val = rs4[j] * acc[m][n][j];
                up[(size_t)(m0 + row + j) * N + col] = (_Float16)val;
                partial = fmaf(wgt, val, partial);
                wgt *= ainv;
            }
        }
        partial += __shfl_xor(partial, 16, 64);
        partial += __shfl_xor(partial, 32, 64);
        if (kg == 0)
            chlast[(size_t)(cb * NCH + cc) * S_DIM + col] = partial;
    }
}

// ---------------------------------------------------------------------------
// GEMM2 fused with scan pass-2:  y = x @ C + D,  x_t = a*x_{t-1} + up_t.
// Block: B(0),B(1) staged -> carry prefix -> 64-step scan -> x-tile to
// resident swizzled LDS -> K-loop with 3-slot B staging (stage kt+2,
// vmcnt(2) = 2-step slack, ONE barrier per iter).
// ---------------------------------------------------------------------------
__global__ __launch_bounds__(256)
void gemm2_scan(const f16* __restrict__ upb, const float* __restrict__ chlast,
                const f16* __restrict__ Ct, const float* __restrict__ Dvec,
                const float* __restrict__ dt, const float* __restrict__ Avec,
                float* __restrict__ y, float* __restrict__ xlast) {
    constexpr int K = S_DIM, N = O_DIM, NK = K / 32;   // 16 k-steps
    __shared__ __align__(16) unsigned char As[64 * 1024];   // 64 KB x-tile
    __shared__ f16 Bs[3][128 * 32];                         // 24 KB
    const int t = threadIdx.x;

    int bid = blockIdx.x;                 // grid = 1024
    bid = (bid & 7) * 128 + (bid >> 3);
    const int n0 = (bid & 7) * 128;       // 8 n-blocks
    const int m0 = (bid >> 3) * 64;       // 128 m-blocks (= b*32 + chunk)
    const int wid = t >> 6, lane = t & 63;
    const int wn = wid * 32, lr = lane & 15, kg = lane >> 4;

    // stage B(0), B(1) early (pre-swizzled source); hide under carry+scan
    const int srcswz = ((t & 3) ^ ((t >> 3) & 3)) * 8;
    const f16* bptr = Ct + (size_t)(n0 + (t >> 2)) * K + srcswz;
    auto stageB = [&](int kt, int slot) {
        load16_lds(bptr + kt * 32, &Bs[slot][t * 8]);
        load16_lds(bptr + (size_t)64 * K + kt * 32, &Bs[slot][2048 + t * 8]);
    };
    stageB(0, 0);
    stageB(1, 1);
    const int rchunk = (kg ^ ((lr >> 1) & 3)) * 8;

    // ---- carry prefix over chunk finals (batched independent loads) ----
    const int cc = (m0 >> 6) & (NCH - 1);
    const int cb = m0 >> 11;
    const int s0 = 2 * t;
    const float dts0 = 1.0f / (1.0f + expf(-dt[s0]));
    const float dts1 = 1.0f / (1.0f + expf(-dt[s0 + 1]));
    const float ab0 = fabsf(Avec[s0]), ab1 = fabsf(Avec[s0 + 1]);
    const float g0 = expf(-dts0 * ab0);
    const float g1 = expf(-dts1 * ab1);
    const float gCL0 = expf(-dts0 * ab0 * (float)CL);
    const float gCL1 = expf(-dts1 * ab1 * (float)CL);
    const float2* ch = (const float2*)chlast;
    float cy0 = 0.f, cy1 = 0.f;
    {
        int j = 0;
        for (; j + 4 <= cc; j += 4) {
            float2 f0 = ch[(size_t)(cb * NCH + j + 0) * 256 + t];
            float2 f1 = ch[(size_t)(cb * NCH + j + 1) * 256 + t];
            float2 f2 = ch[(size_t)(cb * NCH + j + 2) * 256 + t];
            float2 f3 = ch[(size_t)(cb * NCH + j + 3) * 256 + t];
            cy0 = fmaf(gCL0, cy0, f0.x); cy1 = fmaf(gCL1, cy1, f0.y);
            cy0 = fmaf(gCL0, cy0, f1.x); cy1 = fmaf(gCL1, cy1, f1.y);
            cy0 = fmaf(gCL0, cy0, f2.x); cy1 = fmaf(gCL1, cy1, f2.y);
            cy0 = fmaf(gCL0, cy0, f3.x); cy1 = fmaf(gCL1, cy1, f3.y);
        }
        for (; j < cc; ++j) {
            float2 f = ch[(size_t)(cb * NCH + j) * 256 + t];
            cy0 = fmaf(gCL0, cy0, f.x);
            cy1 = fmaf(gCL1, cy1, f.y);
        }
    }

    // ---- load chunk + scan + swizzled LDS write ----
    const unsigned* up32 = (const unsigned*)upb;
    const size_t ub = (size_t)m0 * 256 + t;
    unsigned v[CL];
    #pragma unroll
    for (int j = 0; j < CL; ++j) v[j] = up32[ub + (size_t)j * 256];
    float x0 = cy0, x1 = cy1;
    #pragma unroll
    for (int j = 0; j < CL; ++j) {
        f16x2 h = __builtin_bit_cast(f16x2, v[j]);
        x0 = fmaf(g0, x0, (float)h.x);
        x1 = fmaf(g1, x1, (float)h.y);
        f16x2 o; o.x = (_Float16)x0; o.y = (_Float16)x1;
        v[j] = __builtin_bit_cast(unsigned, o);
    }
    #pragma unroll
    for (int j = 0; j < CL; ++j)
        *(unsigned*)&As[j * 1024 + ((t * 4) ^ ((j & 7) << 4))] = v[j];
    if (cc == NCH - 1)
        ((float2*)xlast)[cb * 256 + t] = make_float2(x0, x1);   // dup across n-blocks, same value
    __syncthreads();   // one-time full drain: scan ds_writes + B(0),B(1)

    // ---- K-loop: A resident in LDS, B 3-slot, one barrier/iter ----
    f32x4 acc[4][2];
    #pragma unroll
    for (int i = 0; i < 4; ++i)
        #pragma unroll
        for (int j = 0; j < 2; ++j) acc[i][j] = (f32x4){0.f, 0.f, 0.f, 0.f};

    const int swz = (lr & 7) << 4;        // row&7 == lr&7 for row = m*16+lr
    #pragma unroll
    for (int kt = 0; kt < NK; ++kt) {
        if (kt > 0) {
            if (kt < NK - 1) asm volatile("s_waitcnt vmcnt(2)");
            else             asm volatile("s_waitcnt vmcnt(0)");
            __builtin_amdgcn_s_barrier();      // prev iter's Bs reads done
            __builtin_amdgcn_sched_barrier(0);
        }
        if (kt + 2 < NK) stageB(kt + 2, (kt + 2) % 3);

        const int slot = kt % 3;
        f16x8 af[4], bf[2];
        #pragma unroll
        for (int m = 0; m < 4; ++m)
            af[m] = *(const f16x8*)&As[(m * 16 + lr) * 1024 + ((kt * 64 + kg * 16) ^ swz)];
        #pragma unroll
        for (int n = 0; n < 2; ++n)
            bf[n] = *(const f16x8*)&Bs[slot][(wn + n * 16 + lr) * 32 + rchunk];
        __builtin_amdgcn_s_setprio(1);
        #pragma unroll
        for (int m = 0; m < 4; ++m)
            #pragma unroll
            for (int n = 0; n < 2; ++n)
                acc[m][n] = __builtin_amdgcn_mfma_f32_16x16x32_f16(af[m], bf[n], acc[m][n], 0, 0, 0);
        __builtin_amdgcn_s_setprio(0);
    }

    // epilogue: y = acc + D
    #pragma unroll
    for (int n = 0; n < 2; ++n) {
        const int col = n0 + wn + n * 16 + lr;
        const float dv = Dvec[col];
        #pragma unroll
        for (int m = 0; m < 4; ++m) {
            const int row = m0 + m * 16 + kg * 4;
            #pragma unroll
            for (int j = 0; j < 4; ++j)
                y[(size_t)(row + j) * N + col] = acc[m][n][j] + dv;
        }
    }
}

// ---------------------------------------------------------------------------
extern "C" void kernel_launch(void* const* d_in, const int* in_sizes, int n_in,
                              void* d_out, int out_size, void* d_ws, size_t ws_size,
                              hipStream_t stream) {
    const float* u    = (const float*)d_in[0];   // [B,T,I]
    const float* dt   = (const float*)d_in[1];   // [S]
    const float* Avec = (const float*)d_in[2];   // [S]
    const float* Bmat = (const float*)d_in[3];   // [I,S]
    const float* Cmat = (const float*)d_in[4];   // [S,O]
    const float* Dvec = (const float*)d_in[5];   // [O]
    const float* nw   = (const float*)d_in[6];   // [I]

    float* y     = (float*)d_out;                      // [B,T,O] fp32
    float* xlast = y + (size_t)M_ROWS * O_DIM;         // [B,S]   fp32

    // workspace (~11 MB)
    char* w = (char*)d_ws;
    f16*            up16   = (f16*)(w);                          // [8192,512] f16
    unsigned short* Bt16   = (unsigned short*)(w + 8388608);     // [512,1024] f16 (dts,nw folded)
    unsigned short* Ct16   = (unsigned short*)(w + 9437184);     // [1024,512] f16
    float*          chlast = (float*)(w + 10485760);             // [B,NCH,S]  fp32

    // 1. weight transposes
    prep_w<<<1024, 256, 0, stream>>>(Bmat, dt, nw, Bt16, Cmat, Ct16);

    // 2. GEMM1 (+rmsnorm +chunk finals): up16 = f16(u)@Bt * rs, chlast
    gemm1_rms_chfin<<<512, 256, 0, stream>>>(u, (const f16*)Bt16, up16, chlast, dt, Avec);

    // 3. GEMM2 (+carry +scan): y, xlast
    gemm2_scan<<<1024, 256, 0, stream>>>(up16, chlast, (const f16*)Ct16, Dvec,
                                         dt, Avec, y, xlast);
}

// Round 11
// 55.491 us; speedup vs baseline: 1.1791x; 1.1791x over previous
//
#include <hip/hip_runtime.h>
#include <math.h>

#define I_DIM 1024
#define S_DIM 512
#define O_DIM 1024
#define T_DIM 2048
#define B_SZ 4
#define M_ROWS (B_SZ * T_DIM)   // 8192
#define EPSF 1e-6f

// scan chunking: chunk length == GEMM BM (64)
#define CL 64
#define NCH 32   // NCH*CL == T_DIM

typedef _Float16 f16;
typedef __attribute__((ext_vector_type(8))) _Float16 f16x8;
typedef __attribute__((ext_vector_type(2))) _Float16 f16x2;
typedef __attribute__((ext_vector_type(4))) float f32x4;

__device__ __forceinline__ unsigned short f2h_bits(float f) {
    _Float16 h = (_Float16)f;
    return __builtin_bit_cast(unsigned short, h);
}

// async 16B global -> LDS (wave-uniform LDS base + lane*16; per-thread dest
// = base + tid*16 matches HW layout exactly -> LINEAR dest only)
__device__ __forceinline__ void load16_lds(const void* g, void* l) {
    __builtin_amdgcn_global_load_lds((const __attribute__((address_space(1))) void*)g,
                                     (__attribute__((address_space(3))) void*)l,
                                     16, 0, 0);
}

// ---------------------------------------------------------------------------
// prep: weight transposes only.
//   blocks [0,512)    : Bt16[s,i] = f16( B[i,s] * sigmoid(dt[s]) * nw[i] )
//   blocks [512,1024) : Ct16[o,s] = f16( C[s,o] )
// ---------------------------------------------------------------------------
__global__ __launch_bounds__(256)
void prep_w(const float* __restrict__ Bmat, const float* __restrict__ dt,
            const float* __restrict__ nw, unsigned short* __restrict__ Bt16,
            const float* __restrict__ Cmat, unsigned short* __restrict__ Ct16) {
    __shared__ float tile[32][33];
    const int t = threadIdx.x;
    const int tx = t & 31, ty = t >> 5;
    const int bx = blockIdx.x;
    if (bx < 512) {
        const int bs = (bx & 15) * 32;   // s block
        const int bi = (bx >> 4) * 32;   // i block
        #pragma unroll
        for (int i = ty; i < 32; i += 8)
            tile[i][tx] = Bmat[(size_t)(bi + i) * S_DIM + bs + tx];
        __syncthreads();
        const float w = nw[bi + tx];
        #pragma unroll
        for (int i = ty; i < 32; i += 8) {
            const int s = bs + i;
            const float dts = 1.0f / (1.0f + expf(-dt[s]));
            Bt16[(size_t)s * I_DIM + bi + tx] = f2h_bits(tile[tx][i] * dts * w);
        }
    } else {
        const int tb = bx - 512;
        const int bo = (tb & 31) * 32;   // o block
        const int bs = (tb >> 5) * 32;   // s block
        #pragma unroll
        for (int i = ty; i < 32; i += 8)
            tile[i][tx] = Cmat[(size_t)(bs + i) * O_DIM + bo + tx];
        __syncthreads();
        #pragma unroll
        for (int i = ty; i < 32; i += 8)
            Ct16[(size_t)(bo + i) * S_DIM + bs + tx] = f2h_bits(tile[tx][i]);
    }
}

// ---------------------------------------------------------------------------
// GEMM1 fused with RMSNorm + scan pass-1.  Reads fp32 u DIRECTLY.
// up[m,s] = rs[m] * sum_i f16(u[m,i]) * Bt[s,i],  rs from in-loop sumsq.
// Pipeline: 3 LDS slots, 3 A-reg sets, 1 barrier/iter; A-regs and B staging
// each get 2 full k-steps of flight time (covers cold-HBM u latency).
// LDS = 36 KB -> 2 blocks/CU at grid 512.
// ---------------------------------------------------------------------------
__global__ __launch_bounds__(256)
void gemm1_rms_chfin(const float* __restrict__ U, const f16* __restrict__ Bt,
                     f16* __restrict__ up, float* __restrict__ chlast,
                     const float* __restrict__ dt, const float* __restrict__ Avec) {
    constexpr int K = I_DIM, N = S_DIM, NK = K / 32;   // 32 k-steps
    __shared__ f16 As[3][64 * 32];    // 12 KB
    __shared__ f16 Bs[3][128 * 32];   // 24 KB
    __shared__ float rsbuf[64];
    const int t = threadIdx.x;

    // XCD swizzle (512 = 8*64): 4 consecutive logical bids share an A panel
    int bid = blockIdx.x;
    bid = (bid & 7) * 64 + (bid >> 3);
    const int n0 = (bid & 3) * 128;       // 4 n-blocks
    const int m0 = (bid >> 2) * 64;       // 128 m-blocks
    const int wid = t >> 6, lane = t & 63;
    const int wn = wid * 32, lr = lane & 15, kg = lane >> 4;

    // source-side chunk swizzle (matches read side)
    const int swch = (t & 3) ^ ((t >> 3) & 3);
    const float* aptr = U + (size_t)(m0 + (t >> 2)) * K + swch * 8;   // fp32 rows
    const f16*  bptr = Bt + (size_t)(n0 + (t >> 2)) * K + swch * 8;   // f16 rows
    const int rchunk = (kg ^ ((lr >> 1) & 3)) * 8;
    f16* adst = (f16*)&As[0][0] + t * 8;                 // + slot*2048

    float ss = 0.f;
    f32x4 acc[4][2];
    #pragma unroll
    for (int i = 0; i < 4; ++i)
        #pragma unroll
        for (int j = 0; j < 2; ++j) acc[i][j] = (f32x4){0.f, 0.f, 0.f, 0.f};

    float4 Ar0[2], Ar1[2], Ar2[2];       // three A reg sets (8 fp32 each)
    auto aset = [&](int i) -> float4* { return i == 0 ? Ar0 : (i == 1 ? Ar1 : Ar2); };

    auto loadA = [&](int kt, float4* r) {
        r[0] = *(const float4*)(aptr + kt * 32);
        r[1] = *(const float4*)(aptr + kt * 32 + 4);
    };
    auto stageB = [&](int kt, int slot) {
        load16_lds(bptr + kt * 32, &Bs[slot][t * 8]);
        load16_lds(bptr + (size_t)64 * K + kt * 32, &Bs[slot][2048 + t * 8]);
    };
    auto writeA = [&](const float4* r, int slot) {
        ss += r[0].x * r[0].x + r[0].y * r[0].y + r[0].z * r[0].z + r[0].w * r[0].w
            + r[1].x * r[1].x + r[1].y * r[1].y + r[1].z * r[1].z + r[1].w * r[1].w;
        f16x8 h = { (_Float16)r[0].x, (_Float16)r[0].y, (_Float16)r[0].z, (_Float16)r[0].w,
                    (_Float16)r[1].x, (_Float16)r[1].y, (_Float16)r[1].z, (_Float16)r[1].w };
        *(f16x8*)(adst + slot * 2048) = h;
    };

    // prologue: A(0),B(0),A(1),B(1),A(2) in flight; write A(0)
    loadA(0, Ar0); stageB(0, 0);
    loadA(1, Ar1); stageB(1, 1);
    loadA(2, Ar2);
    asm volatile("s_waitcnt vmcnt(8)");    // A(0) regs landed
    writeA(Ar0, 0);

    #pragma unroll
    for (int kt = 0; kt < NK; ++kt) {
        asm volatile("s_waitcnt lgkmcnt(0)");          // my ds_write visible
        if (kt <= NK - 3)      asm volatile("s_waitcnt vmcnt(4)");
        else if (kt == NK - 2) asm volatile("s_waitcnt vmcnt(2)");
        else                   asm volatile("s_waitcnt vmcnt(0)");
        __builtin_amdgcn_s_barrier();                  // tile kt fully in LDS
        __builtin_amdgcn_sched_barrier(0);

        if (kt + 1 < NK) writeA(aset((kt + 1) % 3), (kt + 1) % 3);
        if (kt + 3 < NK) loadA(kt + 3, aset((kt + 3) % 3));   // 2-step slack
        if (kt + 2 < NK) stageB(kt + 2, (kt + 2) % 3);

        const int slot = kt % 3;
        f16x8 af[4], bf[2];
        #pragma unroll
        for (int m = 0; m < 4; ++m)
            af[m] = *(const f16x8*)&As[slot][(m * 16 + lr) * 32 + rchunk];
        #pragma unroll
        for (int n = 0; n < 2; ++n)
            bf[n] = *(const f16x8*)&Bs[slot][(wn + n * 16 + lr) * 32 + rchunk];
        __builtin_amdgcn_s_setprio(1);
        #pragma unroll
        for (int m = 0; m < 4; ++m)
            #pragma unroll
            for (int n = 0; n < 2; ++n)
                acc[m][n] = __builtin_amdgcn_mfma_f32_16x16x32_f16(af[m], bf[n], acc[m][n], 0, 0, 0);
        __builtin_amdgcn_s_setprio(0);
    }

    // rs per row: 4 threads share a row -> xor-reduce sumsq
    ss += __shfl_xor(ss, 1, 64);
    ss += __shfl_xor(ss, 2, 64);
    if ((t & 3) == 0) rsbuf[t >> 2] = rsqrtf(ss * (1.0f / K) + EPSF);
    __syncthreads();

    // epilogue: up = rs*acc (f16) + fused chunk-final (fp32)
    // C/D layout: col = lane&15, row = (lane>>4)*4 + reg
    const int cb = m0 >> 11;               // batch
    const int cc = (m0 >> 6) & (NCH - 1);  // chunk
    #pragma unroll
    for (int n = 0; n < 2; ++n) {
        const int col = n0 + wn + n * 16 + lr;
        const float dts = 1.0f / (1.0f + expf(-dt[col]));
        const float e = dts * fabsf(Avec[col]);
        const float ainv = expf(e);        // a^-1
        float partial = 0.f;
        #pragma unroll
        for (int m = 0; m < 4; ++m) {
            const int row = m * 16 + kg * 4;
            f32x4 rs4 = *(const f32x4*)&rsbuf[row];
            float wgt = expf(-e * (float)(63 - row));   // a^(63-row)
            #pragma unroll
            for (int j = 0; j < 4; ++j) {
                const float val = rs4[j] * acc[m][n][j];
                up[(size_t)(m0 + row + j) * N + col] = (_Float16)val;
                partial = fmaf(wgt, val, partial);
                wgt *= ainv;
            }
        }
        partial += __shfl_xor(partial, 16, 64);
        partial += __shfl_xor(partial, 32, 64);
        if (kg == 0)
            chlast[(size_t)(cb * NCH + cc) * S_DIM + col] = partial;
    }
}

// ---------------------------------------------------------------------------
// GEMM2 fused with scan pass-2:  y = x @ C + D,  x_t = a*x_{t-1} + up_t.
// LDS budget EXACTLY 80 KB (As 64 KB + Bs[2] 16 KB) -> 2 blocks/CU.
// (r10's 3rd Bs slot pushed LDS to 88 KB -> 1 block/CU -> 48 us. Reverted.)
// Block: B(0) staged -> batched carry prefix -> 64-step scan -> x-tile to
// resident swizzled LDS -> K-loop (B 2-slot, vmcnt(2), raw barrier pair).
// ---------------------------------------------------------------------------
__global__ __launch_bounds__(256)
void gemm2_scan(const f16* __restrict__ upb, const float* __restrict__ chlast,
                const f16* __restrict__ Ct, const float* __restrict__ Dvec,
                const float* __restrict__ dt, const float* __restrict__ Avec,
                float* __restrict__ y, float* __restrict__ xlast) {
    constexpr int K = S_DIM, N = O_DIM, NK = K / 32;   // 16 k-steps
    __shared__ __align__(16) unsigned char As[64 * 1024];   // 64 KB x-tile
    __shared__ f16 Bs[2][128 * 32];                         // 16 KB
    const int t = threadIdx.x;

    int bid = blockIdx.x;                 // grid = 1024
    bid = (bid & 7) * 128 + (bid >> 3);
    const int n0 = (bid & 7) * 128;       // 8 n-blocks
    const int m0 = (bid >> 3) * 64;       // 128 m-blocks (= b*32 + chunk)
    const int wid = t >> 6, lane = t & 63;
    const int wn = wid * 32, lr = lane & 15, kg = lane >> 4;

    // stage B(0) early (pre-swizzled source); latency hides under carry+scan
    const int srcswz = ((t & 3) ^ ((t >> 3) & 3)) * 8;
    const f16* bptr = Ct + (size_t)(n0 + (t >> 2)) * K + srcswz;
    auto stageB = [&](int kt, int slot) {
        load16_lds(bptr + kt * 32, &Bs[slot][t * 8]);
        load16_lds(bptr + (size_t)64 * K + kt * 32, &Bs[slot][2048 + t * 8]);
    };
    stageB(0, 0);
    const int rchunk = (kg ^ ((lr >> 1) & 3)) * 8;

    // ---- carry prefix over chunk finals (batched independent loads) ----
    const int cc = (m0 >> 6) & (NCH - 1);
    const int cb = m0 >> 11;
    const int s0 = 2 * t;
    const float dts0 = 1.0f / (1.0f + expf(-dt[s0]));
    const float dts1 = 1.0f / (1.0f + expf(-dt[s0 + 1]));
    const float ab0 = fabsf(Avec[s0]), ab1 = fabsf(Avec[s0 + 1]);
    const float g0 = expf(-dts0 * ab0);
    const float g1 = expf(-dts1 * ab1);
    const float gCL0 = expf(-dts0 * ab0 * (float)CL);
    const float gCL1 = expf(-dts1 * ab1 * (float)CL);
    const float2* ch = (const float2*)chlast;
    float cy0 = 0.f, cy1 = 0.f;
    {
        int j = 0;
        for (; j + 4 <= cc; j += 4) {
            float2 f0 = ch[(size_t)(cb * NCH + j + 0) * 256 + t];
            float2 f1 = ch[(size_t)(cb * NCH + j + 1) * 256 + t];
            float2 f2 = ch[(size_t)(cb * NCH + j + 2) * 256 + t];
            float2 f3 = ch[(size_t)(cb * NCH + j + 3) * 256 + t];
            cy0 = fmaf(gCL0, cy0, f0.x); cy1 = fmaf(gCL1, cy1, f0.y);
            cy0 = fmaf(gCL0, cy0, f1.x); cy1 = fmaf(gCL1, cy1, f1.y);
            cy0 = fmaf(gCL0, cy0, f2.x); cy1 = fmaf(gCL1, cy1, f2.y);
            cy0 = fmaf(gCL0, cy0, f3.x); cy1 = fmaf(gCL1, cy1, f3.y);
        }
        for (; j < cc; ++j) {
            float2 f = ch[(size_t)(cb * NCH + j) * 256 + t];
            cy0 = fmaf(gCL0, cy0, f.x);
            cy1 = fmaf(gCL1, cy1, f.y);
        }
    }

    // ---- load chunk + scan + swizzled LDS write ----
    const unsigned* up32 = (const unsigned*)upb;
    const size_t ub = (size_t)m0 * 256 + t;
    unsigned v[CL];
    #pragma unroll
    for (int j = 0; j < CL; ++j) v[j] = up32[ub + (size_t)j * 256];
    float x0 = cy0, x1 = cy1;
    #pragma unroll
    for (int j = 0; j < CL; ++j) {
        f16x2 h = __builtin_bit_cast(f16x2, v[j]);
        x0 = fmaf(g0, x0, (float)h.x);
        x1 = fmaf(g1, x1, (float)h.y);
        f16x2 o; o.x = (_Float16)x0; o.y = (_Float16)x1;
        v[j] = __builtin_bit_cast(unsigned, o);
    }
    #pragma unroll
    for (int j = 0; j < CL; ++j)
        *(unsigned*)&As[j * 1024 + ((t * 4) ^ ((j & 7) << 4))] = v[j];
    if (cc == NCH - 1)
        ((float2*)xlast)[cb * 256 + t] = make_float2(x0, x1);   // dup across n-blocks, same value
    __syncthreads();   // one-time full drain: scan ds_writes + B(0) staging

    // ---- K-loop: A resident in LDS, B double-buffered, counted vmcnt ----
    f32x4 acc[4][2];
    #pragma unroll
    for (int i = 0; i < 4; ++i)
        #pragma unroll
        for (int j = 0; j < 2; ++j) acc[i][j] = (f32x4){0.f, 0.f, 0.f, 0.f};

    const int swz = (lr & 7) << 4;        // row&7 == lr&7 for row = m*16+lr
    for (int kt = 0; kt < NK; ++kt) {
        const int cur = kt & 1;
        if (kt + 1 < NK) {
            stageB(kt + 1, cur ^ 1);
            asm volatile("s_waitcnt vmcnt(2)");   // B[kt] done; B[kt+1] in flight
        } else {
            asm volatile("s_waitcnt vmcnt(0)");
        }
        __builtin_amdgcn_s_barrier();
        __builtin_amdgcn_sched_barrier(0);

        f16x8 af[4], bf[2];
        #pragma unroll
        for (int m = 0; m < 4; ++m)
            af[m] = *(const f16x8*)&As[(m * 16 + lr) * 1024 + ((kt * 64 + kg * 16) ^ swz)];
        #pragma unroll
        for (int n = 0; n < 2; ++n)
            bf[n] = *(const f16x8*)&Bs[cur][(wn + n * 16 + lr) * 32 + rchunk];
        #pragma unroll
        for (int m = 0; m < 4; ++m)
            #pragma unroll
            for (int n = 0; n < 2; ++n)
                acc[m][n] = __builtin_amdgcn_mfma_f32_16x16x32_f16(af[m], bf[n], acc[m][n], 0, 0, 0);
        __builtin_amdgcn_s_barrier();    // Bs[cur] reads done before restage
    }

    // epilogue: y = acc + D
    #pragma unroll
    for (int n = 0; n < 2; ++n) {
        const int col = n0 + wn + n * 16 + lr;
        const float dv = Dvec[col];
        #pragma unroll
        for (int m = 0; m < 4; ++m) {
            const int row = m0 + m * 16 + kg * 4;
            #pragma unroll
            for (int j = 0; j < 4; ++j)
                y[(size_t)(row + j) * N + col] = acc[m][n][j] + dv;
        }
    }
}

// ---------------------------------------------------------------------------
extern "C" void kernel_launch(void* const* d_in, const int* in_sizes, int n_in,
                              void* d_out, int out_size, void* d_ws, size_t ws_size,
                              hipStream_t stream) {
    const float* u    = (const float*)d_in[0];   // [B,T,I]
    const float* dt   = (const float*)d_in[1];   // [S]
    const float* Avec = (const float*)d_in[2];   // [S]
    const float* Bmat = (const float*)d_in[3];   // [I,S]
    const float* Cmat = (const float*)d_in[4];   // [S,O]
    const float* Dvec = (const float*)d_in[5];   // [O]
    const float* nw   = (const float*)d_in[6];   // [I]

    float* y     = (float*)d_out;                      // [B,T,O] fp32
    float* xlast = y + (size_t)M_ROWS * O_DIM;         // [B,S]   fp32

    // workspace (~11 MB)
    char* w = (char*)d_ws;
    f16*            up16   = (f16*)(w);                          // [8192,512] f16
    unsigned short* Bt16   = (unsigned short*)(w + 8388608);     // [512,1024] f16 (dts,nw folded)
    unsigned short* Ct16   = (unsigned short*)(w + 9437184);     // [1024,512] f16
    float*          chlast = (float*)(w + 10485760);             // [B,NCH,S]  fp32

    // 1. weight transposes
    prep_w<<<1024, 256, 0, stream>>>(Bmat, dt, nw, Bt16, Cmat, Ct16);

    // 2. GEMM1 (+rmsnorm +chunk finals): up16 = f16(u)@Bt * rs, chlast
    gemm1_rms_chfin<<<512, 256, 0, stream>>>(u, (const f16*)Bt16, up16, chlast, dt, Avec);

    // 3. GEMM2 (+carry +scan): y, xlast
    gemm2_scan<<<1024, 256, 0, stream>>>(up16, chlast, (const f16*)Ct16, Dvec,
                                         dt, Avec, y, xlast);
}

// Round 12
// 54.347 us; speedup vs baseline: 1.2039x; 1.0211x over previous
//
#include <hip/hip_runtime.h>
#include <math.h>

#define I_DIM 1024
#define S_DIM 512
#define O_DIM 1024
#define T_DIM 2048
#define B_SZ 4
#define M_ROWS (B_SZ * T_DIM)   // 8192
#define EPSF 1e-6f

// scan chunking: chunk length == GEMM BM (64)
#define CL 64
#define NCH 32   // NCH*CL == T_DIM

typedef _Float16 f16;
typedef __attribute__((ext_vector_type(8))) _Float16 f16x8;
typedef __attribute__((ext_vector_type(2))) _Float16 f16x2;
typedef __attribute__((ext_vector_type(4))) float f32x4;

__device__ __forceinline__ unsigned short f2h_bits(float f) {
    _Float16 h = (_Float16)f;
    return __builtin_bit_cast(unsigned short, h);
}

// async 16B global -> LDS (wave-uniform LDS base + lane*16 -> LINEAR dest only)
__device__ __forceinline__ void load16_lds(const void* g, void* l) {
    __builtin_amdgcn_global_load_lds((const __attribute__((address_space(1))) void*)g,
                                     (__attribute__((address_space(3))) void*)l,
                                     16, 0, 0);
}

// ---------------------------------------------------------------------------
// prep: weight transposes only.
//   blocks [0,512)    : Bt16[s,i] = f16( B[i,s] * sigmoid(dt[s]) * nw[i] )
//   blocks [512,1024) : Ct16[o,s] = f16( C[s,o] )
// ---------------------------------------------------------------------------
__global__ __launch_bounds__(256)
void prep_w(const float* __restrict__ Bmat, const float* __restrict__ dt,
            const float* __restrict__ nw, unsigned short* __restrict__ Bt16,
            const float* __restrict__ Cmat, unsigned short* __restrict__ Ct16) {
    __shared__ float tile[32][33];
    const int t = threadIdx.x;
    const int tx = t & 31, ty = t >> 5;
    const int bx = blockIdx.x;
    if (bx < 512) {
        const int bs = (bx & 15) * 32;   // s block
        const int bi = (bx >> 4) * 32;   // i block
        #pragma unroll
        for (int i = ty; i < 32; i += 8)
            tile[i][tx] = Bmat[(size_t)(bi + i) * S_DIM + bs + tx];
        __syncthreads();
        const float w = nw[bi + tx];
        #pragma unroll
        for (int i = ty; i < 32; i += 8) {
            const int s = bs + i;
            const float dts = 1.0f / (1.0f + expf(-dt[s]));
            Bt16[(size_t)s * I_DIM + bi + tx] = f2h_bits(tile[tx][i] * dts * w);
        }
    } else {
        const int tb = bx - 512;
        const int bo = (tb & 31) * 32;   // o block
        const int bs = (tb >> 5) * 32;   // s block
        #pragma unroll
        for (int i = ty; i < 32; i += 8)
            tile[i][tx] = Cmat[(size_t)(bs + i) * O_DIM + bo + tx];
        __syncthreads();
        #pragma unroll
        for (int i = ty; i < 32; i += 8)
            Ct16[(size_t)(bo + i) * S_DIM + bs + tx] = f2h_bits(tile[tx][i]);
    }
}

// ---------------------------------------------------------------------------
// GEMM1 fused with RMSNorm + scan pass-1.  Reads fp32 u DIRECTLY.
// BK=64: 16 k-steps (half the barriers of BK=32), 16-MFMA clusters.
// LDS 72 KB (3 slots x (8KB As + 16KB Bs)) -> still 2 blocks/CU (grid 512).
// Pipeline: 3 LDS slots, 3 A-reg sets (16 fp32 each), 1 barrier/iter;
// steady vmcnt(8) retires {B(kt), A-regs(kt+1)}, keeps {B(kt+1), A(kt+2)}.
// 8-chunk XOR swizzle: LDS chunk c holds global chunk c^(row&7); read chunk
// (sub*4+kg)^(lr&7)  -> even bank distribution for 128B-stride rows.
// ---------------------------------------------------------------------------
__global__ __launch_bounds__(256)
void gemm1_rms_chfin(const float* __restrict__ U, const f16* __restrict__ Bt,
                     f16* __restrict__ up, float* __restrict__ chlast,
                     const float* __restrict__ dt, const float* __restrict__ Avec) {
    constexpr int K = I_DIM, N = S_DIM, NK = K / 64;   // 16 k-steps
    __shared__ f16 As[3][64 * 64];    // 3 x 8 KB
    __shared__ f16 Bs[3][128 * 64];   // 3 x 16 KB
    __shared__ float rsbuf[64];
    const int t = threadIdx.x;

    // XCD swizzle (512 = 8*64): 4 consecutive logical bids share an A panel
    int bid = blockIdx.x;
    bid = (bid & 7) * 64 + (bid >> 3);
    const int n0 = (bid & 3) * 128;       // 4 n-blocks
    const int m0 = (bid >> 2) * 64;       // 128 m-blocks
    const int wid = t >> 6, lane = t & 63;
    const int wn = wid * 32, lr = lane & 15, kg = lane >> 4;

    // A: 4 threads/row, each covers chunks 2(t&3), 2(t&3)+1 (16 f16 = 16 fp32)
    const int arow = t >> 2;
    const int fra = arow & 7;
    const int swzA0 = (2 * (t & 3)) ^ fra;
    const int swzA1 = (2 * (t & 3) + 1) ^ fra;
    const float* aptr = U + (size_t)(m0 + arow) * K;
    f16* adst = (f16*)&As[0][0] + arow * 64 + (t & 3) * 16;   // + slot*4096

    // B: gl_lds x4 per slot; thread t stages row (q*32 + t>>3), LDS chunk t&7
    const int bsw = (t & 7) ^ ((t >> 3) & 7);
    const f16* bptr = Bt + (size_t)(n0 + (t >> 3)) * K + bsw * 8;
    const int rchunk = lr & 7;            // read-side row XOR term

    float ss = 0.f;
    f32x4 acc[4][2];
    #pragma unroll
    for (int i = 0; i < 4; ++i)
        #pragma unroll
        for (int j = 0; j < 2; ++j) acc[i][j] = (f32x4){0.f, 0.f, 0.f, 0.f};

    float4 Ar0[4], Ar1[4], Ar2[4];       // three A reg sets (16 fp32 each)
    auto aset = [&](int i) -> float4* { return i == 0 ? Ar0 : (i == 1 ? Ar1 : Ar2); };

    auto loadA = [&](int kt, float4* r) {
        const float* p = aptr + kt * 64;
        r[0] = *(const float4*)(p + swzA0 * 8);
        r[1] = *(const float4*)(p + swzA0 * 8 + 4);
        r[2] = *(const float4*)(p + swzA1 * 8);
        r[3] = *(const float4*)(p + swzA1 * 8 + 4);
    };
    auto stageB = [&](int kt, int slot) {
        #pragma unroll
        for (int q = 0; q < 4; ++q)
            load16_lds(bptr + (size_t)(q * 32) * K + kt * 64, &Bs[slot][q * 2048 + t * 8]);
    };
    auto writeA = [&](const float4* r, int slot) {
        #pragma unroll
        for (int i = 0; i < 4; ++i)
            ss += r[i].x * r[i].x + r[i].y * r[i].y + r[i].z * r[i].z + r[i].w * r[i].w;
        f16x8 h0 = { (_Float16)r[0].x, (_Float16)r[0].y, (_Float16)r[0].z, (_Float16)r[0].w,
                     (_Float16)r[1].x, (_Float16)r[1].y, (_Float16)r[1].z, (_Float16)r[1].w };
        f16x8 h1 = { (_Float16)r[2].x, (_Float16)r[2].y, (_Float16)r[2].z, (_Float16)r[2].w,
                     (_Float16)r[3].x, (_Float16)r[3].y, (_Float16)r[3].z, (_Float16)r[3].w };
        *(f16x8*)(adst + slot * 4096) = h0;
        *(f16x8*)(adst + slot * 4096 + 8) = h1;
    };

    // prologue: A(0),B(0),A(1),B(1),A(2) in flight (20); wait A(0); write it
    loadA(0, Ar0); stageB(0, 0);
    loadA(1, Ar1); stageB(1, 1);
    loadA(2, Ar2);
    asm volatile("s_waitcnt vmcnt(16)");   // A(0) regs landed
    writeA(Ar0, 0);

    #pragma unroll
    for (int kt = 0; kt < NK; ++kt) {
        asm volatile("s_waitcnt lgkmcnt(0)");          // my ds_writes visible
        if (kt <= NK - 3)      asm volatile("s_waitcnt vmcnt(8)");
        else if (kt == NK - 2) asm volatile("s_waitcnt vmcnt(4)");
        else                   asm volatile("s_waitcnt vmcnt(0)");
        __builtin_amdgcn_s_barrier();                  // tile kt fully in LDS
        __builtin_amdgcn_sched_barrier(0);

        if (kt + 1 < NK) writeA(aset((kt + 1) % 3), (kt + 1) % 3);
        if (kt + 3 < NK) loadA(kt + 3, aset((kt + 3) % 3));   // 2-step slack
        if (kt + 2 < NK) stageB(kt + 2, (kt + 2) % 3);

        const int slot = kt % 3;
        #pragma unroll
        for (int sub = 0; sub < 2; ++sub) {
            const int rc = ((sub * 4 + kg) ^ rchunk) * 8;
            f16x8 af[4], bf[2];
            #pragma unroll
            for (int m = 0; m < 4; ++m)
                af[m] = *(const f16x8*)&As[slot][(m * 16 + lr) * 64 + rc];
            #pragma unroll
            for (int n = 0; n < 2; ++n)
                bf[n] = *(const f16x8*)&Bs[slot][(wn + n * 16 + lr) * 64 + rc];
            __builtin_amdgcn_s_setprio(1);
            #pragma unroll
            for (int m = 0; m < 4; ++m)
                #pragma unroll
                for (int n = 0; n < 2; ++n)
                    acc[m][n] = __builtin_amdgcn_mfma_f32_16x16x32_f16(af[m], bf[n], acc[m][n], 0, 0, 0);
            __builtin_amdgcn_s_setprio(0);
        }
    }

    // rs per row: 4 threads share a row -> xor-reduce sumsq
    ss += __shfl_xor(ss, 1, 64);
    ss += __shfl_xor(ss, 2, 64);
    if ((t & 3) == 0) rsbuf[t >> 2] = rsqrtf(ss * (1.0f / K) + EPSF);
    __syncthreads();

    // epilogue: up = rs*acc (f16) + fused chunk-final (fp32)
    // C/D layout: col = lane&15, row = (lane>>4)*4 + reg
    const int cb = m0 >> 11;               // batch
    const int cc = (m0 >> 6) & (NCH - 1);  // chunk
    #pragma unroll
    for (int n = 0; n < 2; ++n) {
        const int col = n0 + wn + n * 16 + lr;
        const float dts = 1.0f / (1.0f + expf(-dt[col]));
        const float e = dts * fabsf(Avec[col]);
        const float ainv = expf(e);        // a^-1
        float partial = 0.f;
        #pragma unroll
        for (int m = 0; m < 4; ++m) {
            const int row = m * 16 + kg * 4;
            f32x4 rs4 = *(const f32x4*)&rsbuf[row];
            float wgt = expf(-e * (float)(63 - row));   // a^(63-row)
            #pragma unroll
            for (int j = 0; j < 4; ++j) {
                const float val = rs4[j] * acc[m][n][j];
                up[(size_t)(m0 + row + j) * N + col] = (_Float16)val;
                partial = fmaf(wgt, val, partial);
                wgt *= ainv;
            }
        }
        partial += __shfl_xor(partial, 16, 64);
        partial += __shfl_xor(partial, 32, 64);
        if (kg == 0)
            chlast[(size_t)(cb * NCH + cc) * S_DIM + col] = partial;
    }
}

// ---------------------------------------------------------------------------
// GEMM2 fused with scan pass-2:  y = x @ C + D,  x_t = a*x_{t-1} + up_t.
// LDS exactly 80 KB (As 64 KB + Bs[2] 16 KB) -> 2 blocks/CU.
// up-chunk loads issued FIRST (long-latency stream); carry-prefix compute
// overlaps their flight. Then scan -> swizzled resident As -> K-loop
// (B 2-slot, vmcnt(2), raw barrier pair).
// ---------------------------------------------------------------------------
__global__ __launch_bounds__(256)
void gemm2_scan(const f16* __restrict__ upb, const float* __restrict__ chlast,
                const f16* __restrict__ Ct, const float* __restrict__ Dvec,
                const float* __restrict__ dt, const float* __restrict__ Avec,
                float* __restrict__ y, float* __restrict__ xlast) {
    constexpr int K = S_DIM, N = O_DIM, NK = K / 32;   // 16 k-steps
    __shared__ __align__(16) unsigned char As[64 * 1024];   // 64 KB x-tile
    __shared__ f16 Bs[2][128 * 32];                         // 16 KB
    const int t = threadIdx.x;

    int bid = blockIdx.x;                 // grid = 1024
    bid = (bid & 7) * 128 + (bid >> 3);
    const int n0 = (bid & 7) * 128;       // 8 n-blocks
    const int m0 = (bid >> 3) * 64;       // 128 m-blocks (= b*32 + chunk)
    const int wid = t >> 6, lane = t & 63;
    const int wn = wid * 32, lr = lane & 15, kg = lane >> 4;

    // stage B(0) early (pre-swizzled source)
    const int srcswz = ((t & 3) ^ ((t >> 3) & 3)) * 8;
    const f16* bptr = Ct + (size_t)(n0 + (t >> 2)) * K + srcswz;
    auto stageB = [&](int kt, int slot) {
        load16_lds(bptr + kt * 32, &Bs[slot][t * 8]);
        load16_lds(bptr + (size_t)64 * K + kt * 32, &Bs[slot][2048 + t * 8]);
    };
    stageB(0, 0);
    const int rchunk = (kg ^ ((lr >> 1) & 3)) * 8;

    // ---- issue up-chunk loads FIRST (64 independent dwords in flight) ----
    const unsigned* up32 = (const unsigned*)upb;
    const size_t ub = (size_t)m0 * 256 + t;
    unsigned v[CL];
    #pragma unroll
    for (int j = 0; j < CL; ++j) v[j] = up32[ub + (size_t)j * 256];

    // ---- carry prefix over chunk finals (overlaps up-load flight) ----
    const int cc = (m0 >> 6) & (NCH - 1);
    const int cb = m0 >> 11;
    const int s0 = 2 * t;
    const float dts0 = 1.0f / (1.0f + expf(-dt[s0]));
    const float dts1 = 1.0f / (1.0f + expf(-dt[s0 + 1]));
    const float ab0 = fabsf(Avec[s0]), ab1 = fabsf(Avec[s0 + 1]);
    const float g0 = expf(-dts0 * ab0);
    const float g1 = expf(-dts1 * ab1);
    const float gCL0 = expf(-dts0 * ab0 * (float)CL);
    const float gCL1 = expf(-dts1 * ab1 * (float)CL);
    const float2* ch = (const float2*)chlast;
    float cy0 = 0.f, cy1 = 0.f;
    {
        int j = 0;
        for (; j + 4 <= cc; j += 4) {
            float2 f0 = ch[(size_t)(cb * NCH + j + 0) * 256 + t];
            float2 f1 = ch[(size_t)(cb * NCH + j + 1) * 256 + t];
            float2 f2 = ch[(size_t)(cb * NCH + j + 2) * 256 + t];
            float2 f3 = ch[(size_t)(cb * NCH + j + 3) * 256 + t];
            cy0 = fmaf(gCL0, cy0, f0.x); cy1 = fmaf(gCL1, cy1, f0.y);
            cy0 = fmaf(gCL0, cy0, f1.x); cy1 = fmaf(gCL1, cy1, f1.y);
            cy0 = fmaf(gCL0, cy0, f2.x); cy1 = fmaf(gCL1, cy1, f2.y);
            cy0 = fmaf(gCL0, cy0, f3.x); cy1 = fmaf(gCL1, cy1, f3.y);
        }
        for (; j < cc; ++j) {
            float2 f = ch[(size_t)(cb * NCH + j) * 256 + t];
            cy0 = fmaf(gCL0, cy0, f.x);
            cy1 = fmaf(gCL1, cy1, f.y);
        }
    }

    // ---- scan + swizzled LDS write ----
    float x0 = cy0, x1 = cy1;
    #pragma unroll
    for (int j = 0; j < CL; ++j) {
        f16x2 h = __builtin_bit_cast(f16x2, v[j]);
        x0 = fmaf(g0, x0, (float)h.x);
        x1 = fmaf(g1, x1, (float)h.y);
        f16x2 o; o.x = (_Float16)x0; o.y = (_Float16)x1;
        v[j] = __builtin_bit_cast(unsigned, o);
    }
    #pragma unroll
    for (int j = 0; j < CL; ++j)
        *(unsigned*)&As[j * 1024 + ((t * 4) ^ ((j & 7) << 4))] = v[j];
    if (cc == NCH - 1)
        ((float2*)xlast)[cb * 256 + t] = make_float2(x0, x1);   // dup across n-blocks, same value
    __syncthreads();   // one-time full drain: scan ds_writes + B(0) staging

    // ---- K-loop: A resident in LDS, B double-buffered, counted vmcnt ----
    f32x4 acc[4][2];
    #pragma unroll
    for (int i = 0; i < 4; ++i)
        #pragma unroll
        for (int j = 0; j < 2; ++j) acc[i][j] = (f32x4){0.f, 0.f, 0.f, 0.f};

    const int swz = (lr & 7) << 4;        // row&7 == lr&7 for row = m*16+lr
    for (int kt = 0; kt < NK; ++kt) {
        const int cur = kt & 1;
        if (kt + 1 < NK) {
            stageB(kt + 1, cur ^ 1);
            asm volatile("s_waitcnt vmcnt(2)");   // B[kt] done; B[kt+1] in flight
        } else {
            asm volatile("s_waitcnt vmcnt(0)");
        }
        __builtin_amdgcn_s_barrier();
        __builtin_amdgcn_sched_barrier(0);

        f16x8 af[4], bf[2];
        #pragma unroll
        for (int m = 0; m < 4; ++m)
            af[m] = *(const f16x8*)&As[(m * 16 + lr) * 1024 + ((kt * 64 + kg * 16) ^ swz)];
        #pragma unroll
        for (int n = 0; n < 2; ++n)
            bf[n] = *(const f16x8*)&Bs[cur][(wn + n * 16 + lr) * 32 + rchunk];
        __builtin_amdgcn_s_setprio(1);
        #pragma unroll
        for (int m = 0; m < 4; ++m)
            #pragma unroll
            for (int n = 0; n < 2; ++n)
                acc[m][n] = __builtin_amdgcn_mfma_f32_16x16x32_f16(af[m], bf[n], acc[m][n], 0, 0, 0);
        __builtin_amdgcn_s_setprio(0);
        __builtin_amdgcn_s_barrier();    // Bs[cur] reads done before restage
    }

    // epilogue: y = acc + D
    #pragma unroll
    for (int n = 0; n < 2; ++n) {
        const int col = n0 + wn + n * 16 + lr;
        const float dv = Dvec[col];
        #pragma unroll
        for (int m = 0; m < 4; ++m) {
            const int row = m0 + m * 16 + kg * 4;
            #pragma unroll
            for (int j = 0; j < 4; ++j)
                y[(size_t)(row + j) * N + col] = acc[m][n][j] + dv;
        }
    }
}

// ---------------------------------------------------------------------------
extern "C" void kernel_launch(void* const* d_in, const int* in_sizes, int n_in,
                              void* d_out, int out_size, void* d_ws, size_t ws_size,
                              hipStream_t stream) {
    const float* u    = (const float*)d_in[0];   // [B,T,I]
    const float* dt   = (const float*)d_in[1];   // [S]
    const float* Avec = (const float*)d_in[2];   // [S]
    const float* Bmat = (const float*)d_in[3];   // [I,S]
    const float* Cmat = (const float*)d_in[4];   // [S,O]
    const float* Dvec = (const float*)d_in[5];   // [O]
    const float* nw   = (const float*)d_in[6];   // [I]

    float* y     = (float*)d_out;                      // [B,T,O] fp32
    float* xlast = y + (size_t)M_ROWS * O_DIM;         // [B,S]   fp32

    // workspace (~11 MB)
    char* w = (char*)d_ws;
    f16*            up16   = (f16*)(w);                          // [8192,512] f16
    unsigned short* Bt16   = (unsigned short*)(w + 8388608);     // [512,1024] f16 (dts,nw folded)
    unsigned short* Ct16   = (unsigned short*)(w + 9437184);     // [1024,512] f16
    float*          chlast = (float*)(w + 10485760);             // [B,NCH,S]  fp32

    // 1. weight transposes
    prep_w<<<1024, 256, 0, stream>>>(Bmat, dt, nw, Bt16, Cmat, Ct16);

    // 2. GEMM1 (+rmsnorm +chunk finals): up16 = f16(u)@Bt * rs, chlast
    gemm1_rms_chfin<<<512, 256, 0, stream>>>(u, (const f16*)Bt16, up16, chlast, dt, Avec);

    // 3. GEMM2 (+carry +scan): y, xlast
    gemm2_scan<<<1024, 256, 0, stream>>>(up16, chlast, (const f16*)Ct16, Dvec,
                                         dt, Avec, y, xlast);
}